// Round 7
// baseline (542.654 us; speedup 1.0000x reference)
//
#include <hip/hip_runtime.h>
#include <cstdint>

#define FP8MAX 448.0f

typedef float f32x4 __attribute__((ext_vector_type(4)));
typedef int   i32x4 __attribute__((ext_vector_type(4)));
typedef int   i32x8 __attribute__((ext_vector_type(8)));

union frag8 { i32x8 v8; i32x4 v4[2]; };

__device__ __forceinline__ void gload_lds16(const void* g, void* l) {
  __builtin_amdgcn_global_load_lds(
      (const __attribute__((address_space(1))) unsigned int*)g,
      (__attribute__((address_space(3))) unsigned int*)l,
      16, 0, 0);
}

// ---------- quantize x rows: H=2048 floats -> fp8 bytes + per-128-group inv_scale ----------
__global__ __launch_bounds__(256) void quant_x(const float* __restrict__ x,
                                               uint8_t* __restrict__ xq,
                                               float* __restrict__ sa) {
  const int m = blockIdx.x;
  const int t = threadIdx.x;
  const float* xr = x + (size_t)m * 2048;
  float4 v0 = ((const float4*)xr)[t * 2];
  float4 v1 = ((const float4*)xr)[t * 2 + 1];
  float amax = fmaxf(fmaxf(fmaxf(fabsf(v0.x), fabsf(v0.y)), fmaxf(fabsf(v0.z), fabsf(v0.w))),
                     fmaxf(fmaxf(fabsf(v1.x), fabsf(v1.y)), fmaxf(fabsf(v1.z), fabsf(v1.w))));
  #pragma unroll
  for (int off = 1; off < 16; off <<= 1)
    amax = fmaxf(amax, __shfl_xor(amax, off));
  amax = fmaxf(amax, 1e-12f);
  float s   = FP8MAX / amax;   // same op order as reference
  float inv = 1.0f / s;
  if ((t & 15) == 0) sa[(size_t)m * 16 + (t >> 4)] = inv;
  float q[8] = {v0.x * s, v0.y * s, v0.z * s, v0.w * s,
                v1.x * s, v1.y * s, v1.z * s, v1.w * s};
  #pragma unroll
  for (int i = 0; i < 8; ++i) q[i] = fminf(fmaxf(q[i], -FP8MAX), FP8MAX);
  union { unsigned long long u; unsigned int w[2]; } pk;
  pk.w[0] = __builtin_amdgcn_cvt_pk_fp8_f32(q[0], q[1], 0, false);
  pk.w[0] = __builtin_amdgcn_cvt_pk_fp8_f32(q[2], q[3], pk.w[0], true);
  pk.w[1] = __builtin_amdgcn_cvt_pk_fp8_f32(q[4], q[5], 0, false);
  pk.w[1] = __builtin_amdgcn_cvt_pk_fp8_f32(q[6], q[7], pk.w[1], true);
  ((unsigned long long*)(xq + (size_t)m * 2048))[t] = pk.u;
}

// ---------- weight f32 -> fp8 (values are exactly fp8-representable; cast is exact) ----------
__global__ __launch_bounds__(256) void conv_w(const float* __restrict__ w,
                                              uint8_t* __restrict__ w8, int n8) {
  int i = blockIdx.x * 256 + threadIdx.x;
  if (i >= n8) return;
  float4 v0 = ((const float4*)w)[i * 2];
  float4 v1 = ((const float4*)w)[i * 2 + 1];
  union { unsigned long long u; unsigned int x[2]; } pk;
  pk.x[0] = __builtin_amdgcn_cvt_pk_fp8_f32(v0.x, v0.y, 0, false);
  pk.x[0] = __builtin_amdgcn_cvt_pk_fp8_f32(v0.z, v0.w, pk.x[0], true);
  pk.x[1] = __builtin_amdgcn_cvt_pk_fp8_f32(v1.x, v1.y, 0, false);
  pk.x[1] = __builtin_amdgcn_cvt_pk_fp8_f32(v1.z, v1.w, pk.x[1], true);
  ((unsigned long long*)w8)[i] = pk.u;
}

// ---------- block-scaled fp8 GEMM: BM=BN=BK=128, 256 thr (4 waves 2x2),
// per-wave 64x64. A: global->register direct (no LDS). B: LDS double-buffer.
// Counted-vmcnt ring [Bst:4, A:8, Bst:4], wait vmcnt(4), 3 blocks/CU. ----------
__global__ __launch_bounds__(256, 3) void gemm_fp8(
    const uint8_t* __restrict__ A, const uint8_t* __restrict__ Bw,
    const float* __restrict__ sa, const float* __restrict__ sb,
    const float* __restrict__ bias, float* __restrict__ out,
    int M, int N, int K) {
  const int J = K >> 7;               // 16
  const int nbn = N >> 7;             // 16
  int bid = blockIdx.x;
  int nwg = gridDim.x;
  if ((nwg & 7) == 0) {               // T1 XCD chunked swizzle
    int cpx = nwg >> 3;
    bid = (bid & 7) * cpx + (bid >> 3);
  }
  const int bn = bid % nbn;
  const int bm = bid / nbn;
  const int t = threadIdx.x;
  const int lane = t & 63;
  const int w = t >> 6;
  const int wr = w >> 1;              // 0..1  (M band, 64 rows)
  const int wc = w & 1;               // 0..1  (N band, 64 cols)
  const int r16 = lane & 15;
  const int kg = lane >> 4;

  __shared__ __align__(16) uint8_t lB[2][128 * 128];   // 32 KB
  __shared__ __align__(16) float sal[16 * 128];        // 8 KB, [j][row]

  const uint8_t* gA = A + (size_t)bm * 128 * K;
  const uint8_t* gB = Bw + (size_t)bn * 128 * K;

  for (int i = t; i < 128 * 16; i += 256) {
    int row = i >> 4, j = i & 15;
    sal[j * 128 + row] = sa[((size_t)bm * 128 + row) * 16 + j];
  }

  const int sg = t & 7;      // 16B segment

  // stage B K-tile (16KB): 4 gload_lds per thread (4 vmcnt units)
  #define STAGEB(buf_, kt_) do {                                             \
    _Pragma("unroll")                                                        \
    for (int it_ = 0; it_ < 4; ++it_) {                                      \
      int r_ = it_ * 32 + (t >> 3);                                          \
      gload_lds16(gB + (size_t)r_ * K + ((kt_) << 7) + ((sg ^ (r_ & 7)) << 4),\
                  &lB[buf_][r_ * 128 + sg * 16]);                            \
    } } while (0)

  // A fragments: global -> registers, same linear lane->k mapping as B
  // (2 dwordx4 per frag = 8 vmcnt units total)
  #define LOADA(dst_, kt_) do {                                              \
    _Pragma("unroll")                                                        \
    for (int a_ = 0; a_ < 4; ++a_) {                                         \
      const uint8_t* p_ = gA + (size_t)(wr * 64 + a_ * 16 + r16) * K +       \
                          ((kt_) << 7) + kg * 32;                            \
      dst_[a_].v4[0] = *(const i32x4*)p_;                                    \
      dst_[a_].v4[1] = *(const i32x4*)(p_ + 16);                             \
    } } while (0)

  __syncthreads();   // sal visible; drains sal global loads

  frag8 avA[4], avB[4], bv[4];
  f32x4 tot[4][4] = {};
  f32x4 scq[4];
  const f32x4 fz = {0.f, 0.f, 0.f, 0.f};
  const int KT = K >> 7;   // 16

  // prologue queue: [Bst(0):4, A(0):8, Bst(1):4]
  STAGEB(0, 0);
  LOADA(avA, 0);
  STAGEB(1, 1);

  #define BODY(kt_, avC_, avN_) do {                                         \
    const int b_ = (kt_) & 1;                                                \
    asm volatile("s_waitcnt vmcnt(4)" ::: "memory");                         \
    __builtin_amdgcn_s_barrier();                                            \
    asm volatile("" ::: "memory");                                           \
    _Pragma("unroll")                                                        \
    for (int j_ = 0; j_ < 4; ++j_) {                                         \
      int row_ = wc * 64 + j_ * 16 + r16;                                    \
      const uint8_t* bp_ = &lB[b_][row_ * 128];                              \
      int sw_ = (row_ & 7) << 4;                                             \
      bv[j_].v4[0] = *(const i32x4*)(bp_ + ((kg * 32) ^ sw_));               \
      bv[j_].v4[1] = *(const i32x4*)(bp_ + ((kg * 32 + 16) ^ sw_));          \
    }                                                                        \
    const float sbj_ = sb[bn * J + (kt_)];                                   \
    _Pragma("unroll")                                                        \
    for (int a_ = 0; a_ < 4; ++a_)                                           \
      scq[a_] = (*(const f32x4*)&sal[(kt_) * 128 + wr * 64 + a_ * 16 +       \
                                     kg * 4]) * sbj_;                        \
    { const int kn_ = ((kt_) + 1 < KT) ? (kt_) + 1 : 0;                      \
      LOADA(avN_, kn_); }                                                    \
    __builtin_amdgcn_s_setprio(1);                                           \
    _Pragma("unroll")                                                        \
    for (int a_ = 0; a_ < 4; ++a_) { _Pragma("unroll")                       \
      for (int j_ = 0; j_ < 4; ++j_) {                                       \
        f32x4 p_ = __builtin_amdgcn_mfma_scale_f32_16x16x128_f8f6f4(         \
            avC_[a_].v8, bv[j_].v8, fz, 0, 0, 0, 0x7f7f7f7f, 0, 0x7f7f7f7f); \
        tot[a_][j_] += p_ * scq[a_];                                         \
      } }                                                                    \
    __builtin_amdgcn_s_setprio(0);                                           \
    __builtin_amdgcn_s_barrier();                                            \
    asm volatile("" ::: "memory");                                           \
    { const int k2_ = ((kt_) + 2 < KT) ? (kt_) + 2 : (kt_) + 2 - KT;         \
      STAGEB(b_, k2_); }                                                     \
  } while (0)

  for (int kt = 0; kt < KT; kt += 2) {
    BODY(kt, avA, avB);
    BODY(kt + 1, avB, avA);
  }
  asm volatile("s_waitcnt vmcnt(0)" ::: "memory");   // retire junk ring loads

  // epilogue: bias + store (C/D: col = r16, row = kg*4 + r)
  float bb[4];
  #pragma unroll
  for (int j = 0; j < 4; ++j) bb[j] = bias[bn * 128 + wc * 64 + j * 16 + r16];
  #pragma unroll
  for (int a = 0; a < 4; ++a) {
    int row0 = bm * 128 + wr * 64 + a * 16 + kg * 4;
    #pragma unroll
    for (int r = 0; r < 4; ++r) {
      float* orow = out + (size_t)(row0 + r) * N + bn * 128 + wc * 64;
      #pragma unroll
      for (int j = 0; j < 4; ++j)
        orow[j * 16 + r16] = tot[a][j][r] + bb[j];
    }
  }
}

extern "C" void kernel_launch(void* const* d_in, const int* in_sizes, int n_in,
                              void* d_out, int out_size, void* d_ws, size_t ws_size,
                              hipStream_t stream) {
  const float* x    = (const float*)d_in[0];
  const float* wt   = (const float*)d_in[1];
  const float* wsc  = (const float*)d_in[2];
  const float* bias = (const float*)d_in[3];
  float* out = (float*)d_out;

  const int O = in_sizes[3];            // 2048
  const int H = in_sizes[1] / O;        // 2048
  const int M = in_sizes[0] / H;        // 16384

  uint8_t* xq = (uint8_t*)d_ws;                       // M*H bytes
  uint8_t* w8 = xq + (size_t)M * H;                   // O*H bytes
  float*   sa = (float*)(w8 + (size_t)O * H);         // M*(H/128) floats

  quant_x<<<M, 256, 0, stream>>>(x, xq, sa);
  int n8 = O * H / 8;
  conv_w<<<(n8 + 255) / 256, 256, 0, stream>>>(wt, w8, n8);
  int grid = (M / 128) * (O / 128);
  gemm_fp8<<<grid, 256, 0, stream>>>(xq, w8, sa, wsc, bias, out, M, O, H);
}

// Round 8
// 162.446 us; speedup vs baseline: 3.3405x; 3.3405x over previous
//
#include <hip/hip_runtime.h>
#include <cstdint>

#define FP8MAX 448.0f

typedef float f32x4 __attribute__((ext_vector_type(4)));
typedef int   i32x4 __attribute__((ext_vector_type(4)));
typedef int   i32x8 __attribute__((ext_vector_type(8)));

union frag8 { i32x8 v8; i32x4 v4[2]; };

__device__ __forceinline__ void gload_lds16(const void* g, void* l) {
  __builtin_amdgcn_global_load_lds(
      (const __attribute__((address_space(1))) unsigned int*)g,
      (__attribute__((address_space(3))) unsigned int*)l,
      16, 0, 0);
}

// ---------- quantize x rows: H=2048 floats -> fp8 bytes + per-128-group inv_scale ----------
__global__ __launch_bounds__(256) void quant_x(const float* __restrict__ x,
                                               uint8_t* __restrict__ xq,
                                               float* __restrict__ sa) {
  const int m = blockIdx.x;
  const int t = threadIdx.x;
  const float* xr = x + (size_t)m * 2048;
  float4 v0 = ((const float4*)xr)[t * 2];
  float4 v1 = ((const float4*)xr)[t * 2 + 1];
  float amax = fmaxf(fmaxf(fmaxf(fabsf(v0.x), fabsf(v0.y)), fmaxf(fabsf(v0.z), fabsf(v0.w))),
                     fmaxf(fmaxf(fabsf(v1.x), fabsf(v1.y)), fmaxf(fabsf(v1.z), fabsf(v1.w))));
  #pragma unroll
  for (int off = 1; off < 16; off <<= 1)
    amax = fmaxf(amax, __shfl_xor(amax, off));
  amax = fmaxf(amax, 1e-12f);
  float s   = FP8MAX / amax;   // same op order as reference
  float inv = 1.0f / s;
  if ((t & 15) == 0) sa[(size_t)m * 16 + (t >> 4)] = inv;
  float q[8] = {v0.x * s, v0.y * s, v0.z * s, v0.w * s,
                v1.x * s, v1.y * s, v1.z * s, v1.w * s};
  #pragma unroll
  for (int i = 0; i < 8; ++i) q[i] = fminf(fmaxf(q[i], -FP8MAX), FP8MAX);
  union { unsigned long long u; unsigned int w[2]; } pk;
  pk.w[0] = __builtin_amdgcn_cvt_pk_fp8_f32(q[0], q[1], 0, false);
  pk.w[0] = __builtin_amdgcn_cvt_pk_fp8_f32(q[2], q[3], pk.w[0], true);
  pk.w[1] = __builtin_amdgcn_cvt_pk_fp8_f32(q[4], q[5], 0, false);
  pk.w[1] = __builtin_amdgcn_cvt_pk_fp8_f32(q[6], q[7], pk.w[1], true);
  ((unsigned long long*)(xq + (size_t)m * 2048))[t] = pk.u;
}

// ---------- weight f32 -> fp8 (values are exactly fp8-representable; cast is exact) ----------
__global__ __launch_bounds__(256) void conv_w(const float* __restrict__ w,
                                              uint8_t* __restrict__ w8, int n8) {
  int i = blockIdx.x * 256 + threadIdx.x;
  if (i >= n8) return;
  float4 v0 = ((const float4*)w)[i * 2];
  float4 v1 = ((const float4*)w)[i * 2 + 1];
  union { unsigned long long u; unsigned int x[2]; } pk;
  pk.x[0] = __builtin_amdgcn_cvt_pk_fp8_f32(v0.x, v0.y, 0, false);
  pk.x[0] = __builtin_amdgcn_cvt_pk_fp8_f32(v0.z, v0.w, pk.x[0], true);
  pk.x[1] = __builtin_amdgcn_cvt_pk_fp8_f32(v1.x, v1.y, 0, false);
  pk.x[1] = __builtin_amdgcn_cvt_pk_fp8_f32(v1.z, v1.w, pk.x[1], true);
  ((unsigned long long*)w8)[i] = pk.u;
}

// ---------- block-scaled fp8 GEMM, 256x256 tile, 8 waves, 8-phase K-loop.
// Phase form: [reads; vm; stage][BAR][lgkm; MFMA][BAR]  (work BETWEEN barrier
// pairs -> wave drift overlaps one wave's ds_read with another's MFMA). ----------
#define SAL_STRIDE 260

__global__ __launch_bounds__(512, 2) void gemm_fp8(
    const uint8_t* __restrict__ A, const uint8_t* __restrict__ Bw,
    const float* __restrict__ sa, const float* __restrict__ sb,
    const float* __restrict__ bias, float* __restrict__ out,
    int M, int N, int K) {
  const int J = K >> 7;               // 16
  const int nbn = N >> 8;             // 8
  int bid = blockIdx.x;
  int nwg = gridDim.x;
  if ((nwg & 7) == 0) {               // T1 XCD chunked swizzle
    int cpx = nwg >> 3;
    bid = (bid & 7) * cpx + (bid >> 3);
  }
  const int bn = bid % nbn;
  const int bm = bid / nbn;
  const int t = threadIdx.x;
  const int lane = t & 63;
  const int w = t >> 6;
  const int wr = w >> 2;              // 0..1  (M band)
  const int wc = w & 3;               // 0..3  (N band)
  const int r16 = lane & 15;
  const int kg = lane >> 4;

  __shared__ __align__(16) uint8_t lA[2][256 * 128];   // [buf][h*128+row][128B]
  __shared__ __align__(16) uint8_t lB[2][256 * 128];
  __shared__ __align__(16) float sal[16 * SAL_STRIDE];

  const uint8_t* gA = A + (size_t)bm * 256 * K;
  const uint8_t* gB = Bw + (size_t)bn * 256 * K;

  for (int i = t; i < 256 * 16; i += 512) {
    int row = i >> 4, j = i & 15;
    sal[j * SAL_STRIDE + row] = sa[((size_t)bm * 256 + row) * 16 + j];
  }

  const int rl = t >> 3;     // 0..63
  const int sg = t & 7;      // 16B segment

  // stage one half-tile (128 rows x 128B): 2 gload_lds per thread (2 vmcnt units)
  #define STAGE2(ldst, gbase, h_, kt_) do {                                  \
    _Pragma("unroll")                                                        \
    for (int it_ = 0; it_ < 2; ++it_) {                                      \
      int r_ = it_ * 64 + rl;                                                \
      int gr_ = (h_) * 128 + r_;                                             \
      gload_lds16(gbase + (size_t)gr_ * K + ((kt_) << 7) +                   \
                      ((sg ^ (r_ & 7)) << 4),                                \
                  (ldst) + gr_ * 128 + sg * 16);                             \
    } } while (0)

  __syncthreads();   // sal visible; drains sal's global loads

  // prologue FIFO (12 units): Ah0(0) Bh0(0) Ah1Bh1(0) Ah0(1) Bh0(1)
  STAGE2(lA[0], gA, 0, 0);
  STAGE2(lB[0], gB, 0, 0);
  STAGE2(lA[0], gA, 1, 0);
  STAGE2(lB[0], gB, 1, 0);
  STAGE2(lA[1], gA, 0, 1);
  STAGE2(lB[1], gB, 0, 1);
  asm volatile("s_waitcnt vmcnt(4)" ::: "memory");   // tile 0 fully resident
  __builtin_amdgcn_s_barrier();
  asm volatile("" ::: "memory");

  f32x4 tot[8][4] = {};
  const f32x4 fz = {0.f, 0.f, 0.f, 0.f};
  frag8 av[4], bv[2][2];
  f32x4 scq[4];

  #define VM(NN)    asm volatile("s_waitcnt vmcnt(" #NN ")" ::: "memory")
  #define BARN      do { __builtin_amdgcn_s_barrier();                       \
                         asm volatile("" ::: "memory"); } while (0)
  #define MID       do { asm volatile("s_waitcnt lgkmcnt(0)" ::: "memory");  \
                         __builtin_amdgcn_sched_barrier(0); } while (0)

  #define READ_A(mg_, buf_) do { _Pragma("unroll")                           \
    for (int i_ = 0; i_ < 4; ++i_) {                                         \
      int row_ = (mg_) * 128 + wr * 64 + i_ * 16 + r16;                      \
      const uint8_t* bp_ = &lA[buf_][row_ * 128];                            \
      int sw_ = (row_ & 7) << 4;                                             \
      av[i_].v4[0] = *(const i32x4*)(bp_ + ((kg * 32) ^ sw_));               \
      av[i_].v4[1] = *(const i32x4*)(bp_ + ((kg * 32 + 16) ^ sw_));          \
    } } while (0)

  #define READ_B(ng_, buf_) do { _Pragma("unroll")                           \
    for (int j_ = 0; j_ < 2; ++j_) {                                         \
      int row_ = (ng_) * 128 + wc * 32 + j_ * 16 + r16;                      \
      const uint8_t* bp_ = &lB[buf_][row_ * 128];                            \
      int sw_ = (row_ & 7) << 4;                                             \
      bv[ng_][j_].v4[0] = *(const i32x4*)(bp_ + ((kg * 32) ^ sw_));          \
      bv[ng_][j_].v4[1] = *(const i32x4*)(bp_ + ((kg * 32 + 16) ^ sw_));     \
    } } while (0)

  #define CALC_SC(mg_, kt_, sbj_) do { _Pragma("unroll")                     \
    for (int i_ = 0; i_ < 4; ++i_) {                                         \
      scq[i_] = (*(const f32x4*)&sal[(kt_) * SAL_STRIDE + (mg_) * 128 +      \
                                     wr * 64 + i_ * 16 + kg * 4]) * (sbj_);  \
    } } while (0)

  #define MFMA8(mg_, ng_) do {                                               \
    __builtin_amdgcn_s_setprio(1);                                           \
    _Pragma("unroll")                                                        \
    for (int i_ = 0; i_ < 4; ++i_) { _Pragma("unroll")                       \
      for (int j_ = 0; j_ < 2; ++j_) {                                       \
        f32x4 p_ = __builtin_amdgcn_mfma_scale_f32_16x16x128_f8f6f4(         \
            av[i_].v8, bv[ng_][j_].v8, fz, 0, 0, 0, 0x7f7f7f7f, 0,           \
            0x7f7f7f7f);                                                     \
        tot[(mg_) * 4 + i_][(ng_) * 2 + j_] += p_ * scq[i_];                 \
      } }                                                                    \
    __builtin_amdgcn_s_setprio(0); } while (0)

  const int KT = K >> 7;   // 16
  const int NI = KT >> 1;  // 8
  for (int i = 0; i < NI; ++i) {
    const int kt = 2 * i;
    const int kt2 = (kt + 2 < KT) ? kt + 2 : kt + 2 - KT;   // wrapped junk on tail
    const int kt3 = (kt + 3 < KT) ? kt + 3 : kt + 3 - KT;
    const float sb0  = sb[(bn * 2 + 0) * J + kt];
    const float sb1  = sb[(bn * 2 + 1) * J + kt];
    const float sb0n = sb[(bn * 2 + 0) * J + kt + 1];
    const float sb1n = sb[(bn * 2 + 1) * J + kt + 1];
    // ph0: read Ah0,Bh0(kt) | stage Ah1,Bh1(kt+1)
    READ_A(0, 0); READ_B(0, 0); CALC_SC(0, kt, sb0);
    STAGE2(lA[1], gA, 1, kt + 1); STAGE2(lB[1], gB, 1, kt + 1);
    BARN; MID; MFMA8(0, 0); BARN;
    // ph1: read Bh1(kt)
    READ_B(1, 0); CALC_SC(0, kt, sb1);
    BARN; MID; MFMA8(0, 1); BARN;
    // ph2: read Ah1(kt) | stage Ah0(kt+2)
    READ_A(1, 0); CALC_SC(1, kt, sb0);
    STAGE2(lA[0], gA, 0, kt2);
    BARN; MID; MFMA8(1, 0); BARN;
    // ph3: (reuse av, bv1) | vm(6) retires Ah0,Bh0(kt+1) | stage Bh0(kt+2)
    CALC_SC(1, kt, sb1);
    VM(6);
    STAGE2(lB[0], gB, 0, kt2);
    BARN; MID; MFMA8(1, 1); BARN;
    // ph4: read Ah0,Bh0(kt+1) | vm(4) retires Ah1,Bh1(kt+1) | stage Ah1,Bh1(kt+2)
    READ_A(0, 1); READ_B(0, 1); CALC_SC(0, kt + 1, sb0n);
    VM(4);
    STAGE2(lA[0], gA, 1, kt2); STAGE2(lB[0], gB, 1, kt2);
    BARN; MID; MFMA8(0, 0); BARN;
    // ph5: read Bh1(kt+1)
    READ_B(1, 1); CALC_SC(0, kt + 1, sb1n);
    BARN; MID; MFMA8(0, 1); BARN;
    // ph6: read Ah1(kt+1) | stage Ah0(kt+3)
    READ_A(1, 1); CALC_SC(1, kt + 1, sb0n);
    STAGE2(lA[1], gA, 0, kt3);
    BARN; MID; MFMA8(1, 0); BARN;
    // ph7: vm(2) retires everything through kt+2's halves | stage Bh0(kt+3)
    CALC_SC(1, kt + 1, sb1n);
    VM(2);
    STAGE2(lB[1], gB, 0, kt3);
    BARN; MID; MFMA8(1, 1); BARN;
  }
  asm volatile("s_waitcnt vmcnt(0)" ::: "memory");   // retire junk ring loads

  // epilogue: bias + store (C/D: col = r16, row = kg*4 + r)
  #pragma unroll
  for (int ng = 0; ng < 2; ++ng) {
    float bb[2];
    #pragma unroll
    for (int j = 0; j < 2; ++j)
      bb[j] = bias[bn * 256 + ng * 128 + wc * 32 + j * 16 + r16];
    #pragma unroll
    for (int mg = 0; mg < 2; ++mg) {
      #pragma unroll
      for (int i = 0; i < 4; ++i) {
        int row0 = bm * 256 + mg * 128 + wr * 64 + i * 16 + kg * 4;
        #pragma unroll
        for (int r = 0; r < 4; ++r) {
          float* orow = out + (size_t)(row0 + r) * N + bn * 256 + ng * 128 + wc * 32;
          #pragma unroll
          for (int j = 0; j < 2; ++j)
            orow[j * 16 + r16] = tot[mg * 4 + i][ng * 2 + j][r] + bb[j];
        }
      }
    }
  }
}

extern "C" void kernel_launch(void* const* d_in, const int* in_sizes, int n_in,
                              void* d_out, int out_size, void* d_ws, size_t ws_size,
                              hipStream_t stream) {
  const float* x    = (const float*)d_in[0];
  const float* wt   = (const float*)d_in[1];
  const float* wsc  = (const float*)d_in[2];
  const float* bias = (const float*)d_in[3];
  float* out = (float*)d_out;

  const int O = in_sizes[3];            // 2048
  const int H = in_sizes[1] / O;        // 2048
  const int M = in_sizes[0] / H;        // 16384

  uint8_t* xq = (uint8_t*)d_ws;                       // M*H bytes
  uint8_t* w8 = xq + (size_t)M * H;                   // O*H bytes
  float*   sa = (float*)(w8 + (size_t)O * H);         // M*(H/128) floats

  quant_x<<<M, 256, 0, stream>>>(x, xq, sa);
  int n8 = O * H / 8;
  conv_w<<<(n8 + 255) / 256, 256, 0, stream>>>(wt, w8, n8);
  int grid = (M / 256) * (O / 256);
  gemm_fp8<<<grid, 512, 0, stream>>>(xq, w8, sa, wsc, bias, out, M, O, H);
}

// Round 9
// 147.698 us; speedup vs baseline: 3.6741x; 1.0999x over previous
//
#include <hip/hip_runtime.h>
#include <cstdint>

#define FP8MAX 448.0f

typedef float f32x4 __attribute__((ext_vector_type(4)));
typedef int   i32x4 __attribute__((ext_vector_type(4)));
typedef int   i32x8 __attribute__((ext_vector_type(8)));

union frag8 { i32x8 v8; i32x4 v4[2]; };

__device__ __forceinline__ void gload_lds16(const void* g, void* l) {
  __builtin_amdgcn_global_load_lds(
      (const __attribute__((address_space(1))) unsigned int*)g,
      (__attribute__((address_space(3))) unsigned int*)l,
      16, 0, 0);
}

// ---------- quantize x rows: H=2048 floats -> fp8 bytes + per-128-group inv_scale ----------
__global__ __launch_bounds__(256) void quant_x(const float* __restrict__ x,
                                               uint8_t* __restrict__ xq,
                                               float* __restrict__ sa) {
  const int m = blockIdx.x;
  const int t = threadIdx.x;
  const float* xr = x + (size_t)m * 2048;
  float4 v0 = ((const float4*)xr)[t * 2];
  float4 v1 = ((const float4*)xr)[t * 2 + 1];
  float amax = fmaxf(fmaxf(fmaxf(fabsf(v0.x), fabsf(v0.y)), fmaxf(fabsf(v0.z), fabsf(v0.w))),
                     fmaxf(fmaxf(fabsf(v1.x), fabsf(v1.y)), fmaxf(fabsf(v1.z), fabsf(v1.w))));
  #pragma unroll
  for (int off = 1; off < 16; off <<= 1)
    amax = fmaxf(amax, __shfl_xor(amax, off));
  amax = fmaxf(amax, 1e-12f);
  float s   = FP8MAX / amax;   // same op order as reference
  float inv = 1.0f / s;
  if ((t & 15) == 0) sa[(size_t)m * 16 + (t >> 4)] = inv;
  float q[8] = {v0.x * s, v0.y * s, v0.z * s, v0.w * s,
                v1.x * s, v1.y * s, v1.z * s, v1.w * s};
  #pragma unroll
  for (int i = 0; i < 8; ++i) q[i] = fminf(fmaxf(q[i], -FP8MAX), FP8MAX);
  union { unsigned long long u; unsigned int w[2]; } pk;
  pk.w[0] = __builtin_amdgcn_cvt_pk_fp8_f32(q[0], q[1], 0, false);
  pk.w[0] = __builtin_amdgcn_cvt_pk_fp8_f32(q[2], q[3], pk.w[0], true);
  pk.w[1] = __builtin_amdgcn_cvt_pk_fp8_f32(q[4], q[5], 0, false);
  pk.w[1] = __builtin_amdgcn_cvt_pk_fp8_f32(q[6], q[7], pk.w[1], true);
  ((unsigned long long*)(xq + (size_t)m * 2048))[t] = pk.u;
}

// ---------- weight f32 -> fp8 (values are exactly fp8-representable; cast is exact) ----------
__global__ __launch_bounds__(256) void conv_w(const float* __restrict__ w,
                                              uint8_t* __restrict__ w8, int n8) {
  int i = blockIdx.x * 256 + threadIdx.x;
  if (i >= n8) return;
  float4 v0 = ((const float4*)w)[i * 2];
  float4 v1 = ((const float4*)w)[i * 2 + 1];
  union { unsigned long long u; unsigned int x[2]; } pk;
  pk.x[0] = __builtin_amdgcn_cvt_pk_fp8_f32(v0.x, v0.y, 0, false);
  pk.x[0] = __builtin_amdgcn_cvt_pk_fp8_f32(v0.z, v0.w, pk.x[0], true);
  pk.x[1] = __builtin_amdgcn_cvt_pk_fp8_f32(v1.x, v1.y, 0, false);
  pk.x[1] = __builtin_amdgcn_cvt_pk_fp8_f32(v1.z, v1.w, pk.x[1], true);
  ((unsigned long long*)w8)[i] = pk.u;
}

// ---------- block-scaled fp8 GEMM: BM=BN=BK=128, 256 thr = 4 waves (2x2),
// 64x64 per wave, MX MFMA 16x16x128 (unit scales), counted-vmcnt ring,
// 2 blocks/CU (72 KB LDS). R2 geometry + R6 pipeline. ----------
__global__ __launch_bounds__(256, 2) void gemm_fp8(
    const uint8_t* __restrict__ A, const uint8_t* __restrict__ Bw,
    const float* __restrict__ sa, const float* __restrict__ sb,
    const float* __restrict__ bias, float* __restrict__ out,
    int M, int N, int K) {
  const int J = K >> 7;               // 16
  const int nbn = N >> 7;             // 16
  int bid = blockIdx.x;
  int nwg = gridDim.x;
  if ((nwg & 7) == 0) {               // T1 XCD chunked swizzle
    int cpx = nwg >> 3;
    bid = (bid & 7) * cpx + (bid >> 3);
  }
  const int bn = bid % nbn;
  const int bm = bid / nbn;
  const int t = threadIdx.x;
  const int lane = t & 63;
  const int w = t >> 6;
  const int wm = (w >> 1) << 6;       // wave M offset (0/64)
  const int wn = (w & 1) << 6;        // wave N offset (0/64)
  const int r16 = lane & 15;
  const int kg = lane >> 4;

  __shared__ __align__(16) uint8_t lA[2][128 * 128];   // 32 KB
  __shared__ __align__(16) uint8_t lB[2][128 * 128];   // 32 KB
  __shared__ __align__(16) float sal[16 * 128];        // 8 KB, [j][row]

  const uint8_t* gA = A + (size_t)bm * 128 * K;
  const uint8_t* gB = Bw + (size_t)bn * 128 * K;

  // stage inv_scale slab transposed to [j][row]; consecutive lanes write
  // consecutive LDS words (conflict-free); global reads are strided but
  // tiny (8 KB slab, L2-resident).
  for (int i = t; i < 128 * 16; i += 256) {
    int row = i & 127, j = i >> 7;
    sal[j * 128 + row] = sa[((size_t)bm * 128 + row) * 16 + j];
  }

  const int srow = t >> 3;     // 0..31
  const int sg = t & 7;        // 16B segment

  // stage one full K-tile (A 16KB + B 16KB): 8 gload_lds per thread (8 vmcnt units)
  #define STAGE(buf_, kt_) do {                                              \
    _Pragma("unroll")                                                        \
    for (int it_ = 0; it_ < 4; ++it_) {                                      \
      int r_ = srow + it_ * 32;                                              \
      int so_ = ((sg ^ (r_ & 7)) << 4);                                      \
      gload_lds16(gA + (size_t)r_ * K + ((kt_) << 7) + so_,                  \
                  &lA[buf_][r_ * 128 + sg * 16]);                            \
      gload_lds16(gB + (size_t)r_ * K + ((kt_) << 7) + so_,                  \
                  &lB[buf_][r_ * 128 + sg * 16]);                            \
    } } while (0)

  __syncthreads();   // sal visible; drains sal's global loads (vmcnt -> 0)

  STAGE(0, 0);       // 8 outstanding
  STAGE(1, 1);       // 16 outstanding

  f32x4 tot[4][4] = {};
  const f32x4 fz = {0.f, 0.f, 0.f, 0.f};
  frag8 av[4], bv[4];
  f32x4 scq[4];

  int rowA[4], rowB[4];
  #pragma unroll
  for (int a = 0; a < 4; ++a) rowA[a] = wm + a * 16 + r16;
  #pragma unroll
  for (int b = 0; b < 4; ++b) rowB[b] = wn + b * 16 + r16;

  const int KT = K >> 7;   // 16
  for (int kt = 0; kt < KT; ++kt) {
    const int cur = kt & 1;
    // wait: everything except the most recent STAGE (tile kt+1) retired
    asm volatile("s_waitcnt vmcnt(8)" ::: "memory");
    __builtin_amdgcn_s_barrier();
    asm volatile("" ::: "memory");
    // fragment reads (compiler-scheduled lgkmcnt)
    #pragma unroll
    for (int a = 0; a < 4; ++a) {
      const int sw = (rowA[a] & 7) << 4;
      const uint8_t* bp = &lA[cur][rowA[a] * 128];
      av[a].v4[0] = *(const i32x4*)(bp + ((kg * 32) ^ sw));
      av[a].v4[1] = *(const i32x4*)(bp + ((kg * 32 + 16) ^ sw));
    }
    #pragma unroll
    for (int b = 0; b < 4; ++b) {
      const int sw = (rowB[b] & 7) << 4;
      const uint8_t* bp = &lB[cur][rowB[b] * 128];
      bv[b].v4[0] = *(const i32x4*)(bp + ((kg * 32) ^ sw));
      bv[b].v4[1] = *(const i32x4*)(bp + ((kg * 32 + 16) ^ sw));
    }
    const float sbj = sb[bn * J + kt];
    #pragma unroll
    for (int a = 0; a < 4; ++a)
      scq[a] = (*(const f32x4*)&sal[kt * 128 + wm + a * 16 + kg * 4]) * sbj;
    // compute: 16 MX MFMA + fused rescale
    __builtin_amdgcn_s_setprio(1);
    #pragma unroll
    for (int a = 0; a < 4; ++a) {
      #pragma unroll
      for (int b = 0; b < 4; ++b) {
        f32x4 p = __builtin_amdgcn_mfma_scale_f32_16x16x128_f8f6f4(
            av[a].v8, bv[b].v8, fz, 0, 0, 0, 0x7f7f7f7f, 0, 0x7f7f7f7f);
        tot[a][b] += p * scq[a];
      }
    }
    __builtin_amdgcn_s_setprio(0);
    __builtin_amdgcn_s_barrier();      // all waves done reading buf[cur]
    asm volatile("" ::: "memory");
    // stage tile kt+2 into buf[cur]; wrapped junk on last 2 iters keeps the
    // vmcnt FIFO uniform (targets regions already consumed; WAR-safe).
    const int kt2 = (kt + 2 < KT) ? kt + 2 : kt + 2 - KT;
    STAGE(cur, kt2);                   // back to 16 outstanding
  }
  asm volatile("s_waitcnt vmcnt(0)" ::: "memory");   // retire junk ring loads

  // epilogue: bias + store (C/D: col = r16, row = kg*4 + r)
  float bb[4];
  #pragma unroll
  for (int b = 0; b < 4; ++b) bb[b] = bias[bn * 128 + wn + b * 16 + r16];
  #pragma unroll
  for (int a = 0; a < 4; ++a) {
    int row0 = bm * 128 + wm + a * 16 + kg * 4;
    #pragma unroll
    for (int r = 0; r < 4; ++r) {
      float* orow = out + (size_t)(row0 + r) * N + bn * 128;
      #pragma unroll
      for (int b = 0; b < 4; ++b)
        orow[wn + b * 16 + r16] = tot[a][b][r] + bb[b];
    }
  }
}

extern "C" void kernel_launch(void* const* d_in, const int* in_sizes, int n_in,
                              void* d_out, int out_size, void* d_ws, size_t ws_size,
                              hipStream_t stream) {
  const float* x    = (const float*)d_in[0];
  const float* wt   = (const float*)d_in[1];
  const float* wsc  = (const float*)d_in[2];
  const float* bias = (const float*)d_in[3];
  float* out = (float*)d_out;

  const int O = in_sizes[3];            // 2048
  const int H = in_sizes[1] / O;        // 2048
  const int M = in_sizes[0] / H;        // 16384

  uint8_t* xq = (uint8_t*)d_ws;                       // M*H bytes
  uint8_t* w8 = xq + (size_t)M * H;                   // O*H bytes
  float*   sa = (float*)(w8 + (size_t)O * H);         // M*(H/128) floats

  quant_x<<<M, 256, 0, stream>>>(x, xq, sa);
  int n8 = O * H / 8;
  conv_w<<<(n8 + 255) / 256, 256, 0, stream>>>(wt, w8, n8);
  int grid = (M / 128) * (O / 128);
  gemm_fp8<<<grid, 256, 0, stream>>>(xq, w8, sa, wsc, bias, out, M, O, H);
}